// Round 8
// baseline (1385.142 us; speedup 1.0000x reference)
//
#include <hip/hip_runtime.h>
#include <math.h>

static constexpr int L_SEQ  = 3136;
static constexpr int NBATCH = 8;
static constexpr int CDIM   = 384;
static constexpr int DIN    = 768;
static constexpr int NHM    = 12;
static constexpr int HDM    = 64;
static constexpr int DPROJ  = 1676;   // 2*768 + 2*64 + 12
static constexpr int CONVD  = 896;    // 768 + 128
static constexpr int NROWS  = NBATCH * L_SEQ; // 25088
static constexpr int NHA    = 12;
static constexpr int NSEG   = 56;     // scan segments
static constexpr int SEGLEN = 56;     // 3136 / 56

typedef __attribute__((ext_vector_type(8))) short short8;
typedef __attribute__((ext_vector_type(4))) float f32x4;
typedef const unsigned int __attribute__((address_space(1)))* gua_t;
typedef unsigned int __attribute__((address_space(3)))* lua_t;

__device__ __forceinline__ float siluf(float x) { return x / (1.f + __expf(-x)); }
__device__ __forceinline__ unsigned short f2bf(float f) {
  unsigned int u = __float_as_uint(f);
  u += 0x7fff + ((u >> 16) & 1);
  return (unsigned short)(u >> 16);
}
__device__ __forceinline__ float bf2f(unsigned short h) {
  return __uint_as_float(((unsigned int)h) << 16);
}

// ---------------- LayerNorm: one wave per row, C=384, bf16 out ----------------
__global__ __launch_bounds__(256) void ln_kernel(const float* __restrict__ in,
    const float* __restrict__ w, const float* __restrict__ b, unsigned short* __restrict__ out) {
  int wave = threadIdx.x >> 6, lane = threadIdx.x & 63;
  int row = blockIdx.x * 4 + wave;
  if (row >= NROWS) return;
  const float* r = in + (size_t)row * CDIM;
  float2 v[3];
  float s1 = 0.f, s2 = 0.f;
#pragma unroll
  for (int q = 0; q < 3; q++) {
    v[q] = *(const float2*)&r[q * 128 + lane * 2];
    s1 += v[q].x + v[q].y;
    s2 += v[q].x * v[q].x + v[q].y * v[q].y;
  }
#pragma unroll
  for (int o = 32; o > 0; o >>= 1) { s1 += __shfl_xor(s1, o, 64); s2 += __shfl_xor(s2, o, 64); }
  float mu = s1 * (1.f / 384.f);
  float var = s2 * (1.f / 384.f) - mu * mu;
  float rs = rsqrtf(var + 1e-5f);
  unsigned short* o = out + (size_t)row * CDIM;
#pragma unroll
  for (int q = 0; q < 3; q++) {
    int c = q * 128 + lane * 2;
    float2 wv = *(const float2*)&w[c];
    float2 bv = *(const float2*)&b[c];
    float ox = (v[q].x - mu) * rs * wv.x + bv.x;
    float oy = (v[q].y - mu) * rs * wv.y + bv.y;
    unsigned int pk = (unsigned int)f2bf(ox) | ((unsigned int)f2bf(oy) << 16);
    *(unsigned int*)&o[c] = pk;
  }
}

// ---------------- weight convert + transpose: W[K][N] fp32 -> WT[Np][K] bf16 ----------------
__global__ __launch_bounds__(256) void wconv_kernel(const float* __restrict__ W,
    unsigned short* __restrict__ WT, int K, int N, int ldw) {
  __shared__ float tile[32][33];
  int k0 = blockIdx.x * 32, n0 = blockIdx.y * 32;
  int tx = threadIdx.x & 31, ty = threadIdx.x >> 5;
#pragma unroll
  for (int j = 0; j < 4; j++) {
    int k = k0 + ty + j * 8;
    int n = n0 + tx;
    tile[ty + j * 8][tx] = (n < N) ? W[(size_t)k * ldw + n] : 0.f;
  }
  __syncthreads();
#pragma unroll
  for (int j = 0; j < 4; j++) {
    int n = n0 + ty + j * 8;
    int k = k0 + tx;
    WT[(size_t)n * K + k] = f2bf(tile[tx][ty + j * 8]);
  }
}

// ---------------- bf16 MFMA GEMM with global_load_lds staging ----------------
// A: M x K bf16 row-major (lda). WT: Np x K bf16 row-major (zero-padded rows).
// 128x128 tile, BK=32, 4 waves; unpadded [128][32] LDS tiles (lane-contiguous
// for width-16 direct-to-LDS DMA; fragment layout matches m97's proven pattern).
template<int ACT, bool HASBIAS, bool HASRES, bool OUTBF>
__global__ __launch_bounds__(256) void gemm_bf(
    const unsigned short* __restrict__ A, const unsigned short* __restrict__ WT,
    void* __restrict__ Cp, const float* __restrict__ bias,
    const float* __restrict__ res, int ldr,
    int M, int N, int K, int lda, int ldc, int coff)
{
  __shared__ unsigned short As[128][32];
  __shared__ unsigned short Ws[128][32];
  int t = threadIdx.x;
  int m0 = blockIdx.y * 128, n0 = blockIdx.x * 128;
  int lane = t & 63, w = t >> 6;
  int wr = (w >> 1) * 64, wc = (w & 1) * 64;
  int fl = lane & 15, kq = lane >> 4;
  f32x4 acc[4][4];
#pragma unroll
  for (int i = 0; i < 4; i++)
#pragma unroll
    for (int j = 0; j < 4; j++) acc[i][j] = (f32x4)0.f;

  for (int k0 = 0; k0 < K; k0 += 32) {
#pragma unroll
    for (int j = 0; j < 2; j++) {
      int c = j * 256 + t;             // chunk id 0..511 (16B each)
      int row = c >> 2, q = c & 3;
      __builtin_amdgcn_global_load_lds(
          (gua_t)&A[(size_t)(m0 + row) * lda + k0 + q * 8],
          (lua_t)&As[0][0] + (size_t)c * 4, 16, 0, 0);
      __builtin_amdgcn_global_load_lds(
          (gua_t)&WT[(size_t)(n0 + row) * K + k0 + q * 8],
          (lua_t)&Ws[0][0] + (size_t)c * 4, 16, 0, 0);
    }
    __syncthreads();
    short8 af[4], bfr[4];
#pragma unroll
    for (int mi = 0; mi < 4; mi++) af[mi] = *(const short8*)&As[wr + mi * 16 + fl][kq * 8];
#pragma unroll
    for (int ni = 0; ni < 4; ni++) bfr[ni] = *(const short8*)&Ws[wc + ni * 16 + fl][kq * 8];
#pragma unroll
    for (int mi = 0; mi < 4; mi++)
#pragma unroll
      for (int ni = 0; ni < 4; ni++)
        acc[mi][ni] = __builtin_amdgcn_mfma_f32_16x16x32_bf16(af[mi], bfr[ni], acc[mi][ni], 0, 0, 0);
    __syncthreads();
  }
  int rbase = (lane >> 4) * 4, cl = lane & 15;
#pragma unroll
  for (int mi = 0; mi < 4; mi++) {
#pragma unroll
    for (int ni = 0; ni < 4; ni++) {
      int n = n0 + wc + ni * 16 + cl;
      if (n >= N) continue;
#pragma unroll
      for (int r = 0; r < 4; r++) {
        int m = m0 + wr + mi * 16 + rbase + r;
        float v = acc[mi][ni][r];
        if (HASBIAS) v += bias[n];
        if (ACT == 1) v = 0.5f * v * (1.f + erff(v * 0.70710678118654752f));
        if (HASRES) v += res[(size_t)m * ldr + n];
        if (OUTBF) ((unsigned short*)Cp)[(size_t)m * ldc + coff + n] = f2bf(v);
        else       ((float*)Cp)[(size_t)m * ldc + coff + n] = v;
      }
    }
  }
}

// ---------------- dt prep (in-place) ----------------
__global__ void dtprep_kernel(float* __restrict__ DT, const float* __restrict__ dt_bias,
    const float* __restrict__ A_log, float* __restrict__ DA) {
  int idx = blockIdx.x * blockDim.x + threadIdx.x;
  if (idx >= NROWS * NHM) return;
  int h = idx % NHM;
  float v = DT[idx] + dt_bias[h];
  float sp = (v > 20.f) ? v : log1pf(expf(v));
  DT[idx] = sp;
  DA[idx] = expf(-expf(A_log[h]) * sp);
}

// ---------------- depthwise causal conv (k=4) + bias + silu; full ----------------
__global__ void conv_kernel(const float* __restrict__ xbc, const float* __restrict__ cw,
    const float* __restrict__ cb, float* __restrict__ XC) {
  int idx = blockIdx.x * blockDim.x + threadIdx.x;
  if (idx >= NROWS * CONVD) return;
  int c = idx % CONVD;
  int row = idx / CONVD;
  int l = row % L_SEQ;
  float acc = cb[c];
#pragma unroll
  for (int j = 0; j < 4; j++) {
    int ls = l - 3 + j;
    if (ls >= 0) acc += xbc[(size_t)(row - 3 + j) * CONVD + c] * cw[c * 4 + j];
  }
  XC[(size_t)row * CONVD + c] = siluf(acc);
}

// ---------------- scan pass 1: 4 segments per block (one per wave) ----------------
__global__ __launch_bounds__(256) void scan1_kernel(const float* __restrict__ XC,
    const float* __restrict__ dtp, const float* __restrict__ dAv,
    float* __restrict__ H, float* __restrict__ QS) {
  int wv = threadIdx.x >> 6;
  int seg = blockIdx.x * 4 + wv, bh = blockIdx.y;
  int b = bh / NHM, head = bh - b * NHM;
  int p = threadIdx.x & 63;
  float h[64];
#pragma unroll
  for (int n = 0; n < 64; n++) h[n] = 0.f;
  float q = 1.f;
  int l0 = seg * SEGLEN;
  const float* xcb = XC + ((size_t)b * L_SEQ + l0) * CONVD;
  const float* dtb = dtp + ((size_t)b * L_SEQ + l0) * NHM + head;
  const float* dab = dAv + ((size_t)b * L_SEQ + l0) * NHM + head;
  int xcol = head * HDM + p;
  for (int i = 0; i < SEGLEN; i++) {
    const float* rowp = xcb + (size_t)i * CONVD;
    float xv = rowp[xcol];
    float dtv = dtb[(size_t)i * NHM];
    float dav = dab[(size_t)i * NHM];
    float a = dtv * xv;
    const float4* B4 = (const float4*)&rowp[768];
#pragma unroll
    for (int nq = 0; nq < 16; nq++) {
      float4 Bq = B4[nq];
      h[nq * 4 + 0] = h[nq * 4 + 0] * dav + a * Bq.x;
      h[nq * 4 + 1] = h[nq * 4 + 1] * dav + a * Bq.y;
      h[nq * 4 + 2] = h[nq * 4 + 2] * dav + a * Bq.z;
      h[nq * 4 + 3] = h[nq * 4 + 3] * dav + a * Bq.w;
    }
    q *= dav;
  }
  float* Hp = H + ((size_t)bh * NSEG + seg) * 4096 + p * 64;
#pragma unroll
  for (int nq = 0; nq < 16; nq++)
    *(float4*)&Hp[nq * 4] = make_float4(h[nq*4], h[nq*4+1], h[nq*4+2], h[nq*4+3]);
  if (p == 0) QS[bh * NSEG + seg] = q;
}

// ---------------- scan combine ----------------
__global__ __launch_bounds__(64) void scomb_kernel(float* __restrict__ H,
    const float* __restrict__ QS) {
  int bh = blockIdx.x;
  int e = (blockIdx.y * 64 + threadIdx.x) * 4;
  float4 cur = make_float4(0.f, 0.f, 0.f, 0.f);
  for (int s = 0; s < NSEG; s++) {
    float* Hp = H + ((size_t)bh * NSEG + s) * 4096 + e;
    float q = QS[bh * NSEG + s];
    float4 tmp = *(float4*)Hp;
    *(float4*)Hp = cur;
    cur.x = q * cur.x + tmp.x;
    cur.y = q * cur.y + tmp.y;
    cur.z = q * cur.z + tmp.z;
    cur.w = q * cur.w + tmp.w;
  }
}

// ---------------- scan pass 2: 4 segments per block (one per wave) ----------------
__global__ __launch_bounds__(256) void scan2_kernel(const float* __restrict__ XC,
    const float* __restrict__ dtp, const float* __restrict__ dAv,
    const float* __restrict__ H, const float* __restrict__ Dp,
    unsigned short* __restrict__ Ybf) {
  int wv = threadIdx.x >> 6;
  int seg = blockIdx.x * 4 + wv, bh = blockIdx.y;
  int b = bh / NHM, head = bh - b * NHM;
  int p = threadIdx.x & 63;
  float h[64];
  const float* Hp = H + ((size_t)bh * NSEG + seg) * 4096 + p * 64;
#pragma unroll
  for (int nq = 0; nq < 16; nq++) {
    float4 h4 = *(const float4*)&Hp[nq * 4];
    h[nq*4] = h4.x; h[nq*4+1] = h4.y; h[nq*4+2] = h4.z; h[nq*4+3] = h4.w;
  }
  float Dh = Dp[head];
  int l0 = seg * SEGLEN;
  const float* xcb = XC + ((size_t)b * L_SEQ + l0) * CONVD;
  const float* dtb = dtp + ((size_t)b * L_SEQ + l0) * NHM + head;
  const float* dab = dAv + ((size_t)b * L_SEQ + l0) * NHM + head;
  unsigned short* yb = Ybf + ((size_t)b * L_SEQ + l0) * DIN + head * HDM + p;
  int xcol = head * HDM + p;
  for (int i = 0; i < SEGLEN; i++) {
    const float* rowp = xcb + (size_t)i * CONVD;
    float xv = rowp[xcol];
    float dtv = dtb[(size_t)i * NHM];
    float dav = dab[(size_t)i * NHM];
    float a = dtv * xv;
    const float4* B4 = (const float4*)&rowp[768];
    const float4* C4 = (const float4*)&rowp[832];
    float y0 = 0.f, y1 = 0.f, y2 = 0.f, y3 = 0.f;
#pragma unroll
    for (int nq = 0; nq < 16; nq++) {
      float4 Bq = B4[nq];
      float4 Cq = C4[nq];
      h[nq * 4 + 0] = h[nq * 4 + 0] * dav + a * Bq.x;
      h[nq * 4 + 1] = h[nq * 4 + 1] * dav + a * Bq.y;
      h[nq * 4 + 2] = h[nq * 4 + 2] * dav + a * Bq.z;
      h[nq * 4 + 3] = h[nq * 4 + 3] * dav + a * Bq.w;
      y0 += h[nq * 4 + 0] * Cq.x;
      y1 += h[nq * 4 + 1] * Cq.y;
      y2 += h[nq * 4 + 2] * Cq.z;
      y3 += h[nq * 4 + 3] * Cq.w;
    }
    float yp = (y0 + y1) + (y2 + y3) + Dh * xv;
    yb[(size_t)i * DIN] = f2bf(yp);
  }
}

// ---------------- gated RMS norm (full) ----------------
__global__ __launch_bounds__(256) void gate_rms_kernel(unsigned short* __restrict__ Y,
    const float* __restrict__ Z, const float* __restrict__ mw) {
  int wave = threadIdx.x >> 6, lane = threadIdx.x & 63;
  int row = blockIdx.x * 4 + wave;
  if (row >= NROWS) return;
  unsigned short* y = Y + (size_t)row * DIN;
  const float* z = Z + (size_t)row * DIN;
  float g[12];
  float ss = 0.f;
#pragma unroll
  for (int q = 0; q < 3; q++) {
    int c = q * 256 + lane * 4;
    uint2 yu = *(const uint2*)&y[c];
    float4 zv = *(const float4*)&z[c];
    float y0 = bf2f((unsigned short)(yu.x & 0xffff));
    float y1 = bf2f((unsigned short)(yu.x >> 16));
    float y2 = bf2f((unsigned short)(yu.y & 0xffff));
    float y3 = bf2f((unsigned short)(yu.y >> 16));
    float g0 = y0 * siluf(zv.x), g1 = y1 * siluf(zv.y);
    float g2 = y2 * siluf(zv.z), g3 = y3 * siluf(zv.w);
    ss += g0 * g0 + g1 * g1 + g2 * g2 + g3 * g3;
    g[q * 4 + 0] = g0; g[q * 4 + 1] = g1; g[q * 4 + 2] = g2; g[q * 4 + 3] = g3;
  }
#pragma unroll
  for (int o = 32; o > 0; o >>= 1) ss += __shfl_xor(ss, o, 64);
  float rs = rsqrtf(ss * (1.f / 768.f) + 1e-5f);
#pragma unroll
  for (int q = 0; q < 3; q++) {
    int c = q * 256 + lane * 4;
    float4 m = *(const float4*)&mw[c];
    unsigned int lo = (unsigned int)f2bf(g[q*4+0] * rs * m.x) | ((unsigned int)f2bf(g[q*4+1] * rs * m.y) << 16);
    unsigned int hi = (unsigned int)f2bf(g[q*4+2] * rs * m.z) | ((unsigned int)f2bf(g[q*4+3] * rs * m.w) << 16);
    uint2 pk; pk.x = lo; pk.y = hi;
    *(uint2*)&y[c] = pk;
  }
}

// ---------------- attention gate ----------------
__global__ __launch_bounds__(256) void attgate_kernel(const unsigned short* __restrict__ XN,
    const float* __restrict__ gw, const float* __restrict__ gb, float* __restrict__ G) {
  int wave = threadIdx.x >> 6, lane = threadIdx.x & 63;
  int row = blockIdx.x * 4 + wave;
  if (row >= NROWS) return;
  const unsigned short* x = XN + (size_t)row * CDIM;
  float acc[12] = {};
#pragma unroll
  for (int q = 0; q < 6; q++) {
    int k = q * 64 + lane;
    float xv = bf2f(x[k]);
    const float* wr = gw + (size_t)k * 12;
    float4 w0 = *(const float4*)&wr[0];
    float4 w1 = *(const float4*)&wr[4];
    float4 w2 = *(const float4*)&wr[8];
    acc[0] += xv * w0.x; acc[1] += xv * w0.y; acc[2]  += xv * w0.z; acc[3]  += xv * w0.w;
    acc[4] += xv * w1.x; acc[5] += xv * w1.y; acc[6]  += xv * w1.z; acc[7]  += xv * w1.w;
    acc[8] += xv * w2.x; acc[9] += xv * w2.y; acc[10] += xv * w2.z; acc[11] += xv * w2.w;
  }
#pragma unroll
  for (int h = 0; h < 12; h++)
#pragma unroll
    for (int o = 32; o > 0; o >>= 1) acc[h] += __shfl_xor(acc[h], o, 64);
  if (lane == 0) {
#pragma unroll
    for (int h = 0; h < 12; h++) {
      float v = acc[h] + gb[h];
      G[(size_t)row * 12 + h] = 1.f / (1.f + expf(-v));
    }
  }
}

// ---------------- windowed attention; conflict-free LDS layout ----------------
__global__ __launch_bounds__(256) void attn_kernel(const unsigned short* __restrict__ QKV,
    const float* __restrict__ G, unsigned short* __restrict__ XA) {
  __shared__ float qs[49 * 33];
  __shared__ float kst[32 * 52];
  __shared__ float vs[49 * 32];
  __shared__ float ps[49 * 52];
  int blk = blockIdx.x;
  int head = blk % NHA;
  int win = blk / NHA;
  int b = win >> 6;
  int wr = win & 63;
  int wy = wr >> 3, wx = wr & 7;
  int t = threadIdx.x;
  const float scale = 0.17677669529663688f;

  for (int e = t; e < 1568; e += 256) {
    int tok = e >> 5, d = e & 31;
    int iy = tok / 7, ix = tok - iy * 7;
    size_t rl = (size_t)b * L_SEQ + (wy * 7 + iy) * 56 + (wx * 7 + ix);
    const unsigned short* qp = QKV + rl * 1152 + head * 32 + d;
    qs[tok * 33 + d] = bf2f(qp[0]) * scale;
    kst[d * 52 + tok] = bf2f(qp[384]);
    vs[tok * 32 + d] = bf2f(qp[768]);
  }
  if (t < 96) kst[(t & 31) * 52 + 49 + (t >> 5)] = 0.f;
  __syncthreads();

  for (int e = t; e < 637; e += 256) {
    int qi = e / 13, g = e - qi * 13;
    const float* qrow = &qs[qi * 33];
    float4 acc = make_float4(0.f, 0.f, 0.f, 0.f);
#pragma unroll
    for (int dd = 0; dd < 32; dd++) {
      float qv = qrow[dd];
      float4 kv = *(const float4*)&kst[dd * 52 + g * 4];
      acc.x += qv * kv.x; acc.y += qv * kv.y;
      acc.z += qv * kv.z; acc.w += qv * kv.w;
    }
    *(float4*)&ps[qi * 52 + g * 4] = acc;
  }
  __syncthreads();
  if (t < 49) {
    float* pr = &ps[t * 52];
    float m = pr[0];
    for (int j = 1; j < 49; j++) m = fmaxf(m, pr[j]);
    float s = 0.f;
    for (int j = 0; j < 49; j++) { float e2 = expf(pr[j] - m); pr[j] = e2; s += e2; }
    float inv = 1.f / s;
    for (int j = 0; j < 49; j++) pr[j] *= inv;
  }
  __syncthreads();
  for (int e = t; e < 1568; e += 256) {
    int qi = e >> 5, d = e & 31;
    const float* pr = &ps[qi * 52];
    float acc = 0.f;
    for (int j = 0; j < 49; j++) acc += pr[j] * vs[j * 32 + d];
    int iy = qi / 7, ix = qi - iy * 7;
    size_t rg = (size_t)b * L_SEQ + (wy * 7 + iy) * 56 + (wx * 7 + ix);
    float g = G[rg * 12 + head];
    XA[rg * CDIM + head * 32 + d] = f2bf(acc * g);
  }
}

// ---------------- host launch ----------------
extern "C" void kernel_launch(void* const* d_in, const int* in_sizes, int n_in,
                              void* d_out, int out_size, void* d_ws, size_t ws_size,
                              hipStream_t stream) {
  const float* x        = (const float*)d_in[0];
  const float* norm1_w  = (const float*)d_in[1];
  const float* norm1_b  = (const float*)d_in[2];
  const float* W_in     = (const float*)d_in[3];
  const float* conv_w   = (const float*)d_in[4];
  const float* conv_b   = (const float*)d_in[5];
  const float* dt_bias  = (const float*)d_in[6];
  const float* A_log    = (const float*)d_in[7];
  const float* Dp       = (const float*)d_in[8];
  const float* mnorm_w  = (const float*)d_in[9];
  const float* W_out    = (const float*)d_in[10];
  const float* qkv_w    = (const float*)d_in[11];
  const float* qkv_b    = (const float*)d_in[12];
  const float* gate_w   = (const float*)d_in[13];
  const float* gate_b   = (const float*)d_in[14];
  const float* proj_w   = (const float*)d_in[15];
  const float* proj_b   = (const float*)d_in[16];
  const float* fusion_w = (const float*)d_in[17];
  const float* fusion_b = (const float*)d_in[18];
  const float* norm2_w  = (const float*)d_in[19];
  const float* norm2_b  = (const float*)d_in[20];
  const float* fc1_w    = (const float*)d_in[21];
  const float* fc1_b    = (const float*)d_in[22];
  const float* fc2_w    = (const float*)d_in[23];
  const float* fc2_b    = (const float*)d_in[24];
  float* OUT = (float*)d_out;

  float* ws = (float*)d_ws;
  unsigned short* XNBF = (unsigned short*)ws;              // 25088x384 bf16 (4,816,896 fl)
  float* XC_  = ws + 4816896;                              // XC fp32 full; later CATBF+XABF
  float* SCR  = XC_ + 22478848;                            // xBC fp32 -> H -> z fp32 -> QKVbf -> M1bf
  unsigned short* YBF = (unsigned short*)(SCR + 22478848); // 25088x768 bf16
  unsigned short* WT  = (unsigned short*)(SCR + 22478848 + 9633792); // 3,047,424 bf16
  float* DT_ = (float*)(WT + 3047424);                     // 301,056
  float* DA_ = DT_ + 301056;                               // 301,056
  float* G_  = DA_ + 301056;                               // 301,056
  float* QS_ = G_  + 301056;                               // 5,376

  float* H_ = SCR;
  float* Zf = SCR;
  unsigned short* QKVBF = (unsigned short*)SCR;
  unsigned short* M1BF  = (unsigned short*)SCR;
  unsigned short* CATBF = (unsigned short*)XC_;
  unsigned short* XABF  = (unsigned short*)(XC_ + 9633792);

  unsigned short* wt_xbc  = WT;            // 896x384
  unsigned short* wt_dt   = WT + 344064;   // 128x384
  unsigned short* wt_z    = WT + 393216;   // 768x384
  unsigned short* wt_out  = WT + 688128;   // 384x768
  unsigned short* wt_qkv  = WT + 983040;   // 1152x384
  unsigned short* wt_proj = WT + 1425408;  // 384x384
  unsigned short* wt_fus  = WT + 1572864;  // 384x768
  unsigned short* wt_fc1  = WT + 1867776;  // 1536x384
  unsigned short* wt_fc2  = WT + 2457600;  // 384x1536

  wconv_kernel<<<dim3(12,  28), 256, 0, stream>>>(W_in + 768,  wt_xbc,  384,  896, DPROJ);
  wconv_kernel<<<dim3(12,   4), 256, 0, stream>>>(W_in + 1664, wt_dt,   384,   12, DPROJ);
  wconv_kernel<<<dim3(12,  24), 256, 0, stream>>>(W_in,        wt_z,    384,  768, DPROJ);
  wconv_kernel<<<dim3(24,  12), 256, 0, stream>>>(W_out,       wt_out,  768,  384, 384);
  wconv_kernel<<<dim3(12,  36), 256, 0, stream>>>(qkv_w,       wt_qkv,  384, 1152, 1152);
  wconv_kernel<<<dim3(12,  12), 256, 0, stream>>>(proj_w,      wt_proj, 384,  384, 384);
  wconv_kernel<<<dim3(24,  12), 256, 0, stream>>>(fusion_w,    wt_fus,  768,  384, 384);
  wconv_kernel<<<dim3(12,  48), 256, 0, stream>>>(fc1_w,       wt_fc1,  384, 1536, 1536);
  wconv_kernel<<<dim3(48,  12), 256, 0, stream>>>(fc2_w,       wt_fc2, 1536,  384, 384);

  ln_kernel<<<6272, 256, 0, stream>>>(x, norm1_w, norm1_b, XNBF);

  gemm_bf<0, false, false, false><<<dim3(7, 196), 256, 0, stream>>>(
      XNBF, wt_xbc, SCR, nullptr, nullptr, 0, NROWS, CONVD, CDIM, CDIM, CONVD, 0);
  conv_kernel<<<(NROWS * CONVD + 255) / 256, 256, 0, stream>>>(SCR, conv_w, conv_b, XC_);
  gemm_bf<0, false, false, false><<<dim3(1, 196), 256, 0, stream>>>(
      XNBF, wt_dt, DT_, nullptr, nullptr, 0, NROWS, NHM, CDIM, CDIM, NHM, 0);

  dtprep_kernel<<<(NROWS * NHM + 255) / 256, 256, 0, stream>>>(DT_, dt_bias, A_log, DA_);

  scan1_kernel<<<dim3(NSEG / 4, 96), 256, 0, stream>>>(XC_, DT_, DA_, H_, QS_);
  scomb_kernel<<<dim3(96, 16), 64, 0, stream>>>(H_, QS_);
  scan2_kernel<<<dim3(NSEG / 4, 96), 256, 0, stream>>>(XC_, DT_, DA_, H_, Dp, YBF);

  gemm_bf<0, false, false, false><<<dim3(6, 196), 256, 0, stream>>>(
      XNBF, wt_z, Zf, nullptr, nullptr, 0, NROWS, DIN, CDIM, CDIM, DIN, 0);
  gate_rms_kernel<<<6272, 256, 0, stream>>>(YBF, Zf, mnorm_w);

  gemm_bf<0, false, false, true><<<dim3(3, 196), 256, 0, stream>>>(
      YBF, wt_out, CATBF, nullptr, nullptr, 0, NROWS, CDIM, DIN, DIN, 2 * CDIM, 0);

  attgate_kernel<<<6272, 256, 0, stream>>>(XNBF, gate_w, gate_b, G_);

  gemm_bf<0, true, false, true><<<dim3(9, 196), 256, 0, stream>>>(
      XNBF, wt_qkv, QKVBF, qkv_b, nullptr, 0, NROWS, 3 * CDIM, CDIM, CDIM, 3 * CDIM, 0);
  attn_kernel<<<512 * NHA, 256, 0, stream>>>(QKVBF, G_, XABF);

  gemm_bf<0, true, false, true><<<dim3(3, 196), 256, 0, stream>>>(
      XABF, wt_proj, CATBF, proj_b, nullptr, 0, NROWS, CDIM, CDIM, CDIM, 2 * CDIM, CDIM);

  gemm_bf<0, true, true, false><<<dim3(3, 196), 256, 0, stream>>>(
      CATBF, wt_fus, OUT, fusion_b, x, CDIM, NROWS, CDIM, 2 * CDIM, 2 * CDIM, CDIM, 0);

  ln_kernel<<<6272, 256, 0, stream>>>(OUT, norm2_w, norm2_b, XNBF);

  gemm_bf<1, true, false, true><<<dim3(12, 196), 256, 0, stream>>>(
      XNBF, wt_fc1, M1BF, fc1_b, nullptr, 0, NROWS, 4 * CDIM, CDIM, CDIM, 4 * CDIM, 0);
  gemm_bf<0, true, true, false><<<dim3(3, 196), 256, 0, stream>>>(
      M1BF, wt_fc2, OUT, fc2_b, OUT, CDIM, NROWS, CDIM, 4 * CDIM, 4 * CDIM, CDIM, 0);
}

// Round 9
// 1043.093 us; speedup vs baseline: 1.3279x; 1.3279x over previous
//
#include <hip/hip_runtime.h>
#include <math.h>

static constexpr int L_SEQ  = 3136;
static constexpr int NBATCH = 8;
static constexpr int CDIM   = 384;
static constexpr int DIN    = 768;
static constexpr int NHM    = 12;
static constexpr int HDM    = 64;
static constexpr int DPROJ  = 1676;   // 2*768 + 2*64 + 12
static constexpr int CONVD  = 896;    // 768 + 128
static constexpr int NROWS  = NBATCH * L_SEQ; // 25088
static constexpr int NHA    = 12;
static constexpr int NSEG   = 56;     // scan segments
static constexpr int SEGLEN = 56;     // 3136 / 56

typedef __attribute__((ext_vector_type(8))) short short8;
typedef __attribute__((ext_vector_type(4))) float f32x4;
typedef const unsigned int __attribute__((address_space(1)))* gua_t;
typedef unsigned int __attribute__((address_space(3)))* lua_t;

__device__ __forceinline__ float siluf(float x) { return x / (1.f + __expf(-x)); }
__device__ __forceinline__ unsigned short f2bf(float f) {
  unsigned int u = __float_as_uint(f);
  u += 0x7fff + ((u >> 16) & 1);
  return (unsigned short)(u >> 16);
}
__device__ __forceinline__ float bf2f(unsigned short h) {
  return __uint_as_float(((unsigned int)h) << 16);
}

// ---------------- LayerNorm: one wave per row, C=384, bf16 out ----------------
__global__ __launch_bounds__(256) void ln_kernel(const float* __restrict__ in,
    const float* __restrict__ w, const float* __restrict__ b, unsigned short* __restrict__ out) {
  int wave = threadIdx.x >> 6, lane = threadIdx.x & 63;
  int row = blockIdx.x * 4 + wave;
  if (row >= NROWS) return;
  const float* r = in + (size_t)row * CDIM;
  float2 v[3];
  float s1 = 0.f, s2 = 0.f;
#pragma unroll
  for (int q = 0; q < 3; q++) {
    v[q] = *(const float2*)&r[q * 128 + lane * 2];
    s1 += v[q].x + v[q].y;
    s2 += v[q].x * v[q].x + v[q].y * v[q].y;
  }
#pragma unroll
  for (int o = 32; o > 0; o >>= 1) { s1 += __shfl_xor(s1, o, 64); s2 += __shfl_xor(s2, o, 64); }
  float mu = s1 * (1.f / 384.f);
  float var = s2 * (1.f / 384.f) - mu * mu;
  float rs = rsqrtf(var + 1e-5f);
  unsigned short* o = out + (size_t)row * CDIM;
#pragma unroll
  for (int q = 0; q < 3; q++) {
    int c = q * 128 + lane * 2;
    float2 wv = *(const float2*)&w[c];
    float2 bv = *(const float2*)&b[c];
    float ox = (v[q].x - mu) * rs * wv.x + bv.x;
    float oy = (v[q].y - mu) * rs * wv.y + bv.y;
    unsigned int pk = (unsigned int)f2bf(ox) | ((unsigned int)f2bf(oy) << 16);
    *(unsigned int*)&o[c] = pk;
  }
}

// ---------------- weight convert + transpose: W[K][N] fp32 -> WT[Np][K] bf16 ----------------
__global__ __launch_bounds__(256) void wconv_kernel(const float* __restrict__ W,
    unsigned short* __restrict__ WT, int K, int N, int ldw) {
  __shared__ float tile[32][33];
  int k0 = blockIdx.x * 32, n0 = blockIdx.y * 32;
  int tx = threadIdx.x & 31, ty = threadIdx.x >> 5;
#pragma unroll
  for (int j = 0; j < 4; j++) {
    int k = k0 + ty + j * 8;
    int n = n0 + tx;
    tile[ty + j * 8][tx] = (n < N) ? W[(size_t)k * ldw + n] : 0.f;
  }
  __syncthreads();
#pragma unroll
  for (int j = 0; j < 4; j++) {
    int n = n0 + ty + j * 8;
    int k = k0 + tx;
    WT[(size_t)n * K + k] = f2bf(tile[tx][ty + j * 8]);
  }
}

// ---------------- bf16 MFMA GEMM with global_load_lds staging ----------------
template<int ACT, bool HASBIAS, bool HASRES, bool OUTBF>
__global__ __launch_bounds__(256) void gemm_bf(
    const unsigned short* __restrict__ A, const unsigned short* __restrict__ WT,
    void* __restrict__ Cp, const float* __restrict__ bias,
    const float* __restrict__ res, int ldr,
    int M, int N, int K, int lda, int ldc, int coff)
{
  __shared__ unsigned short As[128][32];
  __shared__ unsigned short Ws[128][32];
  int t = threadIdx.x;
  int m0 = blockIdx.y * 128, n0 = blockIdx.x * 128;
  int lane = t & 63, w = t >> 6;
  int wr = (w >> 1) * 64, wc = (w & 1) * 64;
  int fl = lane & 15, kq = lane >> 4;
  f32x4 acc[4][4];
#pragma unroll
  for (int i = 0; i < 4; i++)
#pragma unroll
    for (int j = 0; j < 4; j++) acc[i][j] = (f32x4)0.f;

  for (int k0 = 0; k0 < K; k0 += 32) {
#pragma unroll
    for (int j = 0; j < 2; j++) {
      int c = j * 256 + t;             // chunk id 0..511 (16B each)
      int row = c >> 2, q = c & 3;
      __builtin_amdgcn_global_load_lds(
          (gua_t)&A[(size_t)(m0 + row) * lda + k0 + q * 8],
          (lua_t)&As[0][0] + (size_t)c * 4, 16, 0, 0);
      __builtin_amdgcn_global_load_lds(
          (gua_t)&WT[(size_t)(n0 + row) * K + k0 + q * 8],
          (lua_t)&Ws[0][0] + (size_t)c * 4, 16, 0, 0);
    }
    __syncthreads();
    short8 af[4], bfr[4];
#pragma unroll
    for (int mi = 0; mi < 4; mi++) af[mi] = *(const short8*)&As[wr + mi * 16 + fl][kq * 8];
#pragma unroll
    for (int ni = 0; ni < 4; ni++) bfr[ni] = *(const short8*)&Ws[wc + ni * 16 + fl][kq * 8];
#pragma unroll
    for (int mi = 0; mi < 4; mi++)
#pragma unroll
      for (int ni = 0; ni < 4; ni++)
        acc[mi][ni] = __builtin_amdgcn_mfma_f32_16x16x32_bf16(af[mi], bfr[ni], acc[mi][ni], 0, 0, 0);
    __syncthreads();
  }
  int rbase = (lane >> 4) * 4, cl = lane & 15;
#pragma unroll
  for (int mi = 0; mi < 4; mi++) {
#pragma unroll
    for (int ni = 0; ni < 4; ni++) {
      int n = n0 + wc + ni * 16 + cl;
      if (n >= N) continue;
#pragma unroll
      for (int r = 0; r < 4; r++) {
        int m = m0 + wr + mi * 16 + rbase + r;
        float v = acc[mi][ni][r];
        if (HASBIAS) v += bias[n];
        if (ACT == 1) v = 0.5f * v * (1.f + erff(v * 0.70710678118654752f));
        if (HASRES) v += res[(size_t)m * ldr + n];
        if (OUTBF) ((unsigned short*)Cp)[(size_t)m * ldc + coff + n] = f2bf(v);
        else       ((float*)Cp)[(size_t)m * ldc + coff + n] = v;
      }
    }
  }
}

// ---------------- dt prep (in-place) ----------------
__global__ void dtprep_kernel(float* __restrict__ DT, const float* __restrict__ dt_bias,
    const float* __restrict__ A_log, float* __restrict__ DA) {
  int idx = blockIdx.x * blockDim.x + threadIdx.x;
  if (idx >= NROWS * NHM) return;
  int h = idx % NHM;
  float v = DT[idx] + dt_bias[h];
  float sp = (v > 20.f) ? v : log1pf(expf(v));
  DT[idx] = sp;
  DA[idx] = expf(-expf(A_log[h]) * sp);
}

// ---------------- depthwise causal conv (k=4) + bias + silu; full ----------------
__global__ void conv_kernel(const float* __restrict__ xbc, const float* __restrict__ cw,
    const float* __restrict__ cb, float* __restrict__ XC) {
  int idx = blockIdx.x * blockDim.x + threadIdx.x;
  if (idx >= NROWS * CONVD) return;
  int c = idx % CONVD;
  int row = idx / CONVD;
  int l = row % L_SEQ;
  float acc = cb[c];
#pragma unroll
  for (int j = 0; j < 4; j++) {
    int ls = l - 3 + j;
    if (ls >= 0) acc += xbc[(size_t)(row - 3 + j) * CONVD + c] * cw[c * 4 + j];
  }
  XC[(size_t)row * CONVD + c] = siluf(acc);
}

// ---------------- scan pass 1: one wave per (seg,bh); thread owns p, h[64] in regs ----------------
__global__ __launch_bounds__(64) void scan1_kernel(const float* __restrict__ XC,
    const float* __restrict__ dtp, const float* __restrict__ dAv,
    float* __restrict__ H, float* __restrict__ QS) {
  int seg = blockIdx.x, bh = blockIdx.y;
  int b = bh / NHM, head = bh - b * NHM;
  int p = threadIdx.x;
  float h[64];
#pragma unroll
  for (int n = 0; n < 64; n++) h[n] = 0.f;
  float q = 1.f;
  int l0 = seg * SEGLEN;
  const float* xcb = XC + ((size_t)b * L_SEQ + l0) * CONVD;
  const float* dtb = dtp + ((size_t)b * L_SEQ + l0) * NHM + head;
  const float* dab = dAv + ((size_t)b * L_SEQ + l0) * NHM + head;
  int xcol = head * HDM + p;
  for (int i = 0; i < SEGLEN; i++) {
    const float* rowp = xcb + (size_t)i * CONVD;
    float xv = rowp[xcol];
    float dtv = dtb[(size_t)i * NHM];
    float dav = dab[(size_t)i * NHM];
    float a = dtv * xv;
    const float4* B4 = (const float4*)&rowp[768];
#pragma unroll
    for (int nq = 0; nq < 16; nq++) {
      float4 Bq = B4[nq];
      h[nq * 4 + 0] = h[nq * 4 + 0] * dav + a * Bq.x;
      h[nq * 4 + 1] = h[nq * 4 + 1] * dav + a * Bq.y;
      h[nq * 4 + 2] = h[nq * 4 + 2] * dav + a * Bq.z;
      h[nq * 4 + 3] = h[nq * 4 + 3] * dav + a * Bq.w;
    }
    q *= dav;
  }
  float* Hp = H + ((size_t)bh * NSEG + seg) * 4096 + p * 64;
#pragma unroll
  for (int nq = 0; nq < 16; nq++)
    *(float4*)&Hp[nq * 4] = make_float4(h[nq*4], h[nq*4+1], h[nq*4+2], h[nq*4+3]);
  if (p == 0) QS[bh * NSEG + seg] = q;
}

// ---------------- scan combine ----------------
__global__ __launch_bounds__(64) void scomb_kernel(float* __restrict__ H,
    const float* __restrict__ QS) {
  int bh = blockIdx.x;
  int e = (blockIdx.y * 64 + threadIdx.x) * 4;
  float4 cur = make_float4(0.f, 0.f, 0.f, 0.f);
  for (int s = 0; s < NSEG; s++) {
    float* Hp = H + ((size_t)bh * NSEG + s) * 4096 + e;
    float q = QS[bh * NSEG + s];
    float4 tmp = *(float4*)Hp;
    *(float4*)Hp = cur;
    cur.x = q * cur.x + tmp.x;
    cur.y = q * cur.y + tmp.y;
    cur.z = q * cur.z + tmp.z;
    cur.w = q * cur.w + tmp.w;
  }
}

// ---------------- scan pass 2: one wave per (seg,bh) ----------------
__global__ __launch_bounds__(64) void scan2_kernel(const float* __restrict__ XC,
    const float* __restrict__ dtp, const float* __restrict__ dAv,
    const float* __restrict__ H, const float* __restrict__ Dp,
    unsigned short* __restrict__ Ybf) {
  int seg = blockIdx.x, bh = blockIdx.y;
  int b = bh / NHM, head = bh - b * NHM;
  int p = threadIdx.x;
  float h[64];
  const float* Hp = H + ((size_t)bh * NSEG + seg) * 4096 + p * 64;
#pragma unroll
  for (int nq = 0; nq < 16; nq++) {
    float4 h4 = *(const float4*)&Hp[nq * 4];
    h[nq*4] = h4.x; h[nq*4+1] = h4.y; h[nq*4+2] = h4.z; h[nq*4+3] = h4.w;
  }
  float Dh = Dp[head];
  int l0 = seg * SEGLEN;
  const float* xcb = XC + ((size_t)b * L_SEQ + l0) * CONVD;
  const float* dtb = dtp + ((size_t)b * L_SEQ + l0) * NHM + head;
  const float* dab = dAv + ((size_t)b * L_SEQ + l0) * NHM + head;
  unsigned short* yb = Ybf + ((size_t)b * L_SEQ + l0) * DIN + head * HDM + p;
  int xcol = head * HDM + p;
  for (int i = 0; i < SEGLEN; i++) {
    const float* rowp = xcb + (size_t)i * CONVD;
    float xv = rowp[xcol];
    float dtv = dtb[(size_t)i * NHM];
    float dav = dab[(size_t)i * NHM];
    float a = dtv * xv;
    const float4* B4 = (const float4*)&rowp[768];
    const float4* C4 = (const float4*)&rowp[832];
    float y0 = 0.f, y1 = 0.f, y2 = 0.f, y3 = 0.f;
#pragma unroll
    for (int nq = 0; nq < 16; nq++) {
      float4 Bq = B4[nq];
      float4 Cq = C4[nq];
      h[nq * 4 + 0] = h[nq * 4 + 0] * dav + a * Bq.x;
      h[nq * 4 + 1] = h[nq * 4 + 1] * dav + a * Bq.y;
      h[nq * 4 + 2] = h[nq * 4 + 2] * dav + a * Bq.z;
      h[nq * 4 + 3] = h[nq * 4 + 3] * dav + a * Bq.w;
      y0 += h[nq * 4 + 0] * Cq.x;
      y1 += h[nq * 4 + 1] * Cq.y;
      y2 += h[nq * 4 + 2] * Cq.z;
      y3 += h[nq * 4 + 3] * Cq.w;
    }
    float yp = (y0 + y1) + (y2 + y3) + Dh * xv;
    yb[(size_t)i * DIN] = f2bf(yp);
  }
}

// ---------------- gated RMS norm (full) ----------------
__global__ __launch_bounds__(256) void gate_rms_kernel(unsigned short* __restrict__ Y,
    const float* __restrict__ Z, const float* __restrict__ mw) {
  int wave = threadIdx.x >> 6, lane = threadIdx.x & 63;
  int row = blockIdx.x * 4 + wave;
  if (row >= NROWS) return;
  unsigned short* y = Y + (size_t)row * DIN;
  const float* z = Z + (size_t)row * DIN;
  float g[12];
  float ss = 0.f;
#pragma unroll
  for (int q = 0; q < 3; q++) {
    int c = q * 256 + lane * 4;
    uint2 yu = *(const uint2*)&y[c];
    float4 zv = *(const float4*)&z[c];
    float y0 = bf2f((unsigned short)(yu.x & 0xffff));
    float y1 = bf2f((unsigned short)(yu.x >> 16));
    float y2 = bf2f((unsigned short)(yu.y & 0xffff));
    float y3 = bf2f((unsigned short)(yu.y >> 16));
    float g0 = y0 * siluf(zv.x), g1 = y1 * siluf(zv.y);
    float g2 = y2 * siluf(zv.z), g3 = y3 * siluf(zv.w);
    ss += g0 * g0 + g1 * g1 + g2 * g2 + g3 * g3;
    g[q * 4 + 0] = g0; g[q * 4 + 1] = g1; g[q * 4 + 2] = g2; g[q * 4 + 3] = g3;
  }
#pragma unroll
  for (int o = 32; o > 0; o >>= 1) ss += __shfl_xor(ss, o, 64);
  float rs = rsqrtf(ss * (1.f / 768.f) + 1e-5f);
#pragma unroll
  for (int q = 0; q < 3; q++) {
    int c = q * 256 + lane * 4;
    float4 m = *(const float4*)&mw[c];
    unsigned int lo = (unsigned int)f2bf(g[q*4+0] * rs * m.x) | ((unsigned int)f2bf(g[q*4+1] * rs * m.y) << 16);
    unsigned int hi = (unsigned int)f2bf(g[q*4+2] * rs * m.z) | ((unsigned int)f2bf(g[q*4+3] * rs * m.w) << 16);
    uint2 pk; pk.x = lo; pk.y = hi;
    *(uint2*)&y[c] = pk;
  }
}

// ---------------- attention gate ----------------
__global__ __launch_bounds__(256) void attgate_kernel(const unsigned short* __restrict__ XN,
    const float* __restrict__ gw, const float* __restrict__ gb, float* __restrict__ G) {
  int wave = threadIdx.x >> 6, lane = threadIdx.x & 63;
  int row = blockIdx.x * 4 + wave;
  if (row >= NROWS) return;
  const unsigned short* x = XN + (size_t)row * CDIM;
  float acc[12] = {};
#pragma unroll
  for (int q = 0; q < 6; q++) {
    int k = q * 64 + lane;
    float xv = bf2f(x[k]);
    const float* wr = gw + (size_t)k * 12;
    float4 w0 = *(const float4*)&wr[0];
    float4 w1 = *(const float4*)&wr[4];
    float4 w2 = *(const float4*)&wr[8];
    acc[0] += xv * w0.x; acc[1] += xv * w0.y; acc[2]  += xv * w0.z; acc[3]  += xv * w0.w;
    acc[4] += xv * w1.x; acc[5] += xv * w1.y; acc[6]  += xv * w1.z; acc[7]  += xv * w1.w;
    acc[8] += xv * w2.x; acc[9] += xv * w2.y; acc[10] += xv * w2.z; acc[11] += xv * w2.w;
  }
#pragma unroll
  for (int h = 0; h < 12; h++)
#pragma unroll
    for (int o = 32; o > 0; o >>= 1) acc[h] += __shfl_xor(acc[h], o, 64);
  if (lane == 0) {
#pragma unroll
    for (int h = 0; h < 12; h++) {
      float v = acc[h] + gb[h];
      G[(size_t)row * 12 + h] = 1.f / (1.f + expf(-v));
    }
  }
}

// ---------------- windowed attention; conflict-free LDS layout ----------------
__global__ __launch_bounds__(256) void attn_kernel(const unsigned short* __restrict__ QKV,
    const float* __restrict__ G, unsigned short* __restrict__ XA) {
  __shared__ float qs[49 * 33];
  __shared__ float kst[32 * 52];
  __shared__ float vs[49 * 32];
  __shared__ float ps[49 * 52];
  int blk = blockIdx.x;
  int head = blk % NHA;
  int win = blk / NHA;
  int b = win >> 6;
  int wr = win & 63;
  int wy = wr >> 3, wx = wr & 7;
  int t = threadIdx.x;
  const float scale = 0.17677669529663688f;

  for (int e = t; e < 1568; e += 256) {
    int tok = e >> 5, d = e & 31;
    int iy = tok / 7, ix = tok - iy * 7;
    size_t rl = (size_t)b * L_SEQ + (wy * 7 + iy) * 56 + (wx * 7 + ix);
    const unsigned short* qp = QKV + rl * 1152 + head * 32 + d;
    qs[tok * 33 + d] = bf2f(qp[0]) * scale;
    kst[d * 52 + tok] = bf2f(qp[384]);
    vs[tok * 32 + d] = bf2f(qp[768]);
  }
  if (t < 96) kst[(t & 31) * 52 + 49 + (t >> 5)] = 0.f;
  __syncthreads();

  for (int e = t; e < 637; e += 256) {
    int qi = e / 13, g = e - qi * 13;
    const float* qrow = &qs[qi * 33];
    float4 acc = make_float4(0.f, 0.f, 0.f, 0.f);
#pragma unroll
    for (int dd = 0; dd < 32; dd++) {
      float qv = qrow[dd];
      float4 kv = *(const float4*)&kst[dd * 52 + g * 4];
      acc.x += qv * kv.x; acc.y += qv * kv.y;
      acc.z += qv * kv.z; acc.w += qv * kv.w;
    }
    *(float4*)&ps[qi * 52 + g * 4] = acc;
  }
  __syncthreads();
  if (t < 49) {
    float* pr = &ps[t * 52];
    float m = pr[0];
    for (int j = 1; j < 49; j++) m = fmaxf(m, pr[j]);
    float s = 0.f;
    for (int j = 0; j < 49; j++) { float e2 = expf(pr[j] - m); pr[j] = e2; s += e2; }
    float inv = 1.f / s;
    for (int j = 0; j < 49; j++) pr[j] *= inv;
  }
  __syncthreads();
  for (int e = t; e < 1568; e += 256) {
    int qi = e >> 5, d = e & 31;
    const float* pr = &ps[qi * 52];
    float acc = 0.f;
    for (int j = 0; j < 49; j++) acc += pr[j] * vs[j * 32 + d];
    int iy = qi / 7, ix = qi - iy * 7;
    size_t rg = (size_t)b * L_SEQ + (wy * 7 + iy) * 56 + (wx * 7 + ix);
    float g = G[rg * 12 + head];
    XA[rg * CDIM + head * 32 + d] = f2bf(acc * g);
  }
}

// ---------------- host launch ----------------
extern "C" void kernel_launch(void* const* d_in, const int* in_sizes, int n_in,
                              void* d_out, int out_size, void* d_ws, size_t ws_size,
                              hipStream_t stream) {
  const float* x        = (const float*)d_in[0];
  const float* norm1_w  = (const float*)d_in[1];
  const float* norm1_b  = (const float*)d_in[2];
  const float* W_in     = (const float*)d_in[3];
  const float* conv_w   = (const float*)d_in[4];
  const float* conv_b   = (const float*)d_in[5];
  const float* dt_bias  = (const float*)d_in[6];
  const float* A_log    = (const float*)d_in[7];
  const float* Dp       = (const float*)d_in[8];
  const float* mnorm_w  = (const float*)d_in[9];
  const float* W_out    = (const float*)d_in[10];
  const float* qkv_w    = (const float*)d_in[11];
  const float* qkv_b    = (const float*)d_in[12];
  const float* gate_w   = (const float*)d_in[13];
  const float* gate_b   = (const float*)d_in[14];
  const float* proj_w   = (const float*)d_in[15];
  const float* proj_b   = (const float*)d_in[16];
  const float* fusion_w = (const float*)d_in[17];
  const float* fusion_b = (const float*)d_in[18];
  const float* norm2_w  = (const float*)d_in[19];
  const float* norm2_b  = (const float*)d_in[20];
  const float* fc1_w    = (const float*)d_in[21];
  const float* fc1_b    = (const float*)d_in[22];
  const float* fc2_w    = (const float*)d_in[23];
  const float* fc2_b    = (const float*)d_in[24];
  float* OUT = (float*)d_out;

  float* ws = (float*)d_ws;
  unsigned short* XNBF = (unsigned short*)ws;              // 25088x384 bf16 (4,816,896 fl)
  float* XC_  = ws + 4816896;                              // XC fp32 full; later CATBF+XABF
  float* SCR  = XC_ + 22478848;                            // xBC fp32 -> H -> z fp32 -> QKVbf -> M1bf
  unsigned short* YBF = (unsigned short*)(SCR + 22478848); // 25088x768 bf16
  unsigned short* WT  = (unsigned short*)(SCR + 22478848 + 9633792); // 3,047,424 bf16
  float* DT_ = (float*)(WT + 3047424);                     // 301,056
  float* DA_ = DT_ + 301056;                               // 301,056
  float* G_  = DA_ + 301056;                               // 301,056
  float* QS_ = G_  + 301056;                               // 5,376

  float* H_ = SCR;
  float* Zf = SCR;
  unsigned short* QKVBF = (unsigned short*)SCR;
  unsigned short* M1BF  = (unsigned short*)SCR;
  unsigned short* CATBF = (unsigned short*)XC_;
  unsigned short* XABF  = (unsigned short*)(XC_ + 9633792);

  unsigned short* wt_xbc  = WT;            // 896x384
  unsigned short* wt_dt   = WT + 344064;   // 128x384
  unsigned short* wt_z    = WT + 393216;   // 768x384
  unsigned short* wt_out  = WT + 688128;   // 384x768
  unsigned short* wt_qkv  = WT + 983040;   // 1152x384
  unsigned short* wt_proj = WT + 1425408;  // 384x384
  unsigned short* wt_fus  = WT + 1572864;  // 384x768
  unsigned short* wt_fc1  = WT + 1867776;  // 1536x384
  unsigned short* wt_fc2  = WT + 2457600;  // 384x1536

  wconv_kernel<<<dim3(12,  28), 256, 0, stream>>>(W_in + 768,  wt_xbc,  384,  896, DPROJ);
  wconv_kernel<<<dim3(12,   4), 256, 0, stream>>>(W_in + 1664, wt_dt,   384,   12, DPROJ);
  wconv_kernel<<<dim3(12,  24), 256, 0, stream>>>(W_in,        wt_z,    384,  768, DPROJ);
  wconv_kernel<<<dim3(24,  12), 256, 0, stream>>>(W_out,       wt_out,  768,  384, 384);
  wconv_kernel<<<dim3(12,  36), 256, 0, stream>>>(qkv_w,       wt_qkv,  384, 1152, 1152);
  wconv_kernel<<<dim3(12,  12), 256, 0, stream>>>(proj_w,      wt_proj, 384,  384, 384);
  wconv_kernel<<<dim3(24,  12), 256, 0, stream>>>(fusion_w,    wt_fus,  768,  384, 384);
  wconv_kernel<<<dim3(12,  48), 256, 0, stream>>>(fc1_w,       wt_fc1,  384, 1536, 1536);
  wconv_kernel<<<dim3(48,  12), 256, 0, stream>>>(fc2_w,       wt_fc2, 1536,  384, 384);

  ln_kernel<<<6272, 256, 0, stream>>>(x, norm1_w, norm1_b, XNBF);

  gemm_bf<0, false, false, false><<<dim3(7, 196), 256, 0, stream>>>(
      XNBF, wt_xbc, SCR, nullptr, nullptr, 0, NROWS, CONVD, CDIM, CDIM, CONVD, 0);
  conv_kernel<<<(NROWS * CONVD + 255) / 256, 256, 0, stream>>>(SCR, conv_w, conv_b, XC_);
  gemm_bf<0, false, false, false><<<dim3(1, 196), 256, 0, stream>>>(
      XNBF, wt_dt, DT_, nullptr, nullptr, 0, NROWS, NHM, CDIM, CDIM, NHM, 0);

  dtprep_kernel<<<(NROWS * NHM + 255) / 256, 256, 0, stream>>>(DT_, dt_bias, A_log, DA_);

  scan1_kernel<<<dim3(NSEG, 96), 64, 0, stream>>>(XC_, DT_, DA_, H_, QS_);
  scomb_kernel<<<dim3(96, 16), 64, 0, stream>>>(H_, QS_);
  scan2_kernel<<<dim3(NSEG, 96), 64, 0, stream>>>(XC_, DT_, DA_, H_, Dp, YBF);

  gemm_bf<0, false, false, false><<<dim3(6, 196), 256, 0, stream>>>(
      XNBF, wt_z, Zf, nullptr, nullptr, 0, NROWS, DIN, CDIM, CDIM, DIN, 0);
  gate_rms_kernel<<<6272, 256, 0, stream>>>(YBF, Zf, mnorm_w);

  gemm_bf<0, false, false, true><<<dim3(3, 196), 256, 0, stream>>>(
      YBF, wt_out, CATBF, nullptr, nullptr, 0, NROWS, CDIM, DIN, DIN, 2 * CDIM, 0);

  attgate_kernel<<<6272, 256, 0, stream>>>(XNBF, gate_w, gate_b, G_);

  gemm_bf<0, true, false, true><<<dim3(9, 196), 256, 0, stream>>>(
      XNBF, wt_qkv, QKVBF, qkv_b, nullptr, 0, NROWS, 3 * CDIM, CDIM, CDIM, 3 * CDIM, 0);
  attn_kernel<<<512 * NHA, 256, 0, stream>>>(QKVBF, G_, XABF);

  gemm_bf<0, true, false, true><<<dim3(3, 196), 256, 0, stream>>>(
      XABF, wt_proj, CATBF, proj_b, nullptr, 0, NROWS, CDIM, CDIM, CDIM, 2 * CDIM, CDIM);

  gemm_bf<0, true, true, false><<<dim3(3, 196), 256, 0, stream>>>(
      CATBF, wt_fus, OUT, fusion_b, x, CDIM, NROWS, CDIM, 2 * CDIM, 2 * CDIM, CDIM, 0);

  ln_kernel<<<6272, 256, 0, stream>>>(OUT, norm2_w, norm2_b, XNBF);

  gemm_bf<1, true, false, true><<<dim3(12, 196), 256, 0, stream>>>(
      XNBF, wt_fc1, M1BF, fc1_b, nullptr, 0, NROWS, 4 * CDIM, CDIM, CDIM, 4 * CDIM, 0);
  gemm_bf<0, true, true, false><<<dim3(3, 196), 256, 0, stream>>>(
      M1BF, wt_fc2, OUT, fc2_b, OUT, CDIM, NROWS, CDIM, 4 * CDIM, 4 * CDIM, CDIM, 0);
}